// Round 5
// baseline (160.855 us; speedup 1.0000x reference)
//
#include <hip/hip_runtime.h>
#include <hip/hip_bf16.h>

#define S_LEN 2048
#define BATCH 2
#define DMODEL 1024
#define NHEAD 16
#define HDIM 64
#define MTOT (S_LEN * BATCH)
#define QKV_ELEMS ((size_t)MTOT * DMODEL)

typedef __bf16 bf16x8 __attribute__((ext_vector_type(8)));
typedef unsigned short u16x8 __attribute__((ext_vector_type(8)));
typedef float f32x4 __attribute__((ext_vector_type(4)));
typedef float f32x16 __attribute__((ext_vector_type(16)));
typedef unsigned int u32x4 __attribute__((ext_vector_type(4)));

__device__ __forceinline__ unsigned short f2bf(float f) {
    unsigned int u = __float_as_uint(f);
    u += 0x7FFFu + ((u >> 16) & 1u);
    return (unsigned short)(u >> 16);
}

__device__ __forceinline__ void gload_lds16(const void* g, void* l) {
    __builtin_amdgcn_global_load_lds(
        (const __attribute__((address_space(1))) unsigned int*)g,
        (__attribute__((address_space(3))) unsigned int*)l, 16, 0, 0);
}

// ---------------------------------------------------------------------------
// Projection GEMM (unchanged, verified R1-R3): x @ W^T + b, bf16 out.
// Q: [b][h][s][d] scaled by 0.125*log2(e).  K: [b][h][s][d].  V: [b][h][d][s].
// ---------------------------------------------------------------------------
#define PBM 128
#define PBN 128
#define PBK 32
#define PLDS 48
#define QSCALE 0.18033688011112042f   // 0.125 * log2(e)

__global__ __launch_bounds__(256) void proj_kernel(
        const float* __restrict__ Xq, const float* __restrict__ Xk,
        const float* __restrict__ Xv, const float* __restrict__ Wq,
        const float* __restrict__ Wk, const float* __restrict__ Wv,
        const float* __restrict__ bq, const float* __restrict__ bk,
        const float* __restrict__ bv, unsigned short* __restrict__ ws)
{
    const int t = blockIdx.z;
    const float* X    = (t == 0) ? Xq : (t == 1) ? Xk : Xv;
    const float* W    = (t == 0) ? Wq : (t == 1) ? Wk : Wv;
    const float* bias = (t == 0) ? bq : (t == 1) ? bk : bv;
    unsigned short* out = ws + (size_t)t * QKV_ELEMS;
    const float scale = (t == 0) ? QSCALE : 1.0f;

    __shared__ __align__(16) unsigned short lds[(PBM + PBN) * PLDS];
    unsigned short* Alds = lds;
    unsigned short* Blds = lds + PBM * PLDS;

    const int tid = threadIdx.x;
    const int m0 = blockIdx.y * PBM;
    const int n0 = blockIdx.x * PBN;

    const int wave = tid >> 6;
    const int lane = tid & 63;
    const int lrow = lane & 15;
    const int lg   = lane >> 4;
    const int wr = (wave >> 1) * 64;
    const int wc = (wave & 1) * 64;

    f32x4 acc[4][4];
#pragma unroll
    for (int i = 0; i < 4; ++i)
#pragma unroll
        for (int j = 0; j < 4; ++j)
            acc[i][j] = (f32x4){0.f, 0.f, 0.f, 0.f};

    const int sr = tid >> 3;
    const int sg = tid & 7;

    for (int k0 = 0; k0 < DMODEL; k0 += PBK) {
        __syncthreads();
#pragma unroll
        for (int it = 0; it < 4; ++it) {
            const int row = sr + it * 32;
            const float4 va = *(const float4*)(X + (size_t)(m0 + row) * DMODEL + k0 + sg * 4);
            const float4 vb = *(const float4*)(W + (size_t)(n0 + row) * DMODEL + k0 + sg * 4);
            ushort4 ha, hb;
            ha.x = f2bf(va.x); ha.y = f2bf(va.y); ha.z = f2bf(va.z); ha.w = f2bf(va.w);
            hb.x = f2bf(vb.x); hb.y = f2bf(vb.y); hb.z = f2bf(vb.z); hb.w = f2bf(vb.w);
            *(ushort4*)&Alds[row * PLDS + sg * 4] = ha;
            *(ushort4*)&Blds[row * PLDS + sg * 4] = hb;
        }
        __syncthreads();

        bf16x8 af[4], bw[4];
#pragma unroll
        for (int i = 0; i < 4; ++i) {
            af[i] = *(const bf16x8*)&Alds[(wr + i * 16 + lrow) * PLDS + lg * 8];
            bw[i] = *(const bf16x8*)&Blds[(wc + i * 16 + lrow) * PLDS + lg * 8];
        }
#pragma unroll
        for (int i = 0; i < 4; ++i)
#pragma unroll
            for (int j = 0; j < 4; ++j)
                acc[i][j] = __builtin_amdgcn_mfma_f32_16x16x32_bf16(af[i], bw[j], acc[i][j], 0, 0, 0);
    }

#pragma unroll
    for (int j = 0; j < 4; ++j) {
        const int n  = n0 + wc + j * 16 + lrow;
        const float bv_ = bias[n];
        const int h  = n >> 6;
        const int dd = n & 63;
#pragma unroll
        for (int i = 0; i < 4; ++i) {
#pragma unroll
            for (int r = 0; r < 4; ++r) {
                const int m = m0 + wr + i * 16 + lg * 4 + r;
                const int s = m >> 1;
                const int b = m & 1;
                const float v = (acc[i][j][r] + bv_) * scale;
                size_t idx;
                if (t == 2)
                    idx = ((size_t)((b * NHEAD + h) * HDIM + dd)) * S_LEN + s;
                else
                    idx = ((size_t)((b * NHEAD + h) * S_LEN + s)) * HDIM + dd;
                out[idx] = f2bf(v);
            }
        }
    }
}

// ---------------------------------------------------------------------------
// Flash attention, swapped-QK^T 32x32, double-buffered 1-barrier pipeline:
//   512 blocks x 256 threads (4 waves x 32 q).  KVBLK=64, 32 tiles.
//   Stage tile t+1 via global_load_lds (16B, pre-swizzled global source,
//   linear LDS dest) BEFORE computing tile t; one barrier per tile.
//   Softmax in-register, base-2, defer-max (THR=8).  P via per-wave LDS
//   roundtrip with the same slot->key map as V (layout-invariant PV).
// ---------------------------------------------------------------------------
#define NT (S_LEN / 64)

__global__ __launch_bounds__(256) void attn_kernel(
        const unsigned short* __restrict__ ws, float* __restrict__ out)
{
    const unsigned short* Qw = ws;
    const unsigned short* Kw = ws + QKV_ELEMS;
    const unsigned short* Vw = ws + 2 * QKV_ELEMS;   // [b][h][d][s]

    // 512 blocks: 4 bh per XCD, 16 q-chunks of 128 per bh
    const int bid = blockIdx.x;
    const int idx = bid >> 3;                        // 0..63
    const int bh  = (bid & 7) * 4 + (idx >> 4);      // 0..31
    const int q0  = (idx & 15) * 128;

    __shared__ __align__(16) unsigned short Kbuf[2][64 * 64];
    __shared__ __align__(16) unsigned short Vbuf[2][64 * 64];
    __shared__ unsigned int Pu[4][32 * 32];          // per-wave [keypair][q]

    const int tid  = threadIdx.x;
    const int wave = tid >> 6;
    const int lane = tid & 63;
    const int l31  = lane & 31;
    const int half = lane >> 5;

    const size_t base = (size_t)bh * S_LEN * HDIM;
    const int qrow = q0 + wave * 32 + l31;

    // Q^T B-fragments: lane covers q = l31, d = c*16 + half*8 + j
    bf16x8 qf[4];
#pragma unroll
    for (int c = 0; c < 4; ++c)
        qf[c] = *(const bf16x8*)(Qw + base + (size_t)qrow * HDIM + c * 16 + half * 8);

    f32x16 Od0, Od1;
#pragma unroll
    for (int i = 0; i < 16; ++i) { Od0[i] = 0.f; Od1[i] = 0.f; }
    float mrun = -__builtin_inff();
    float lrun = 0.f;

    // staging coords (constant across tiles): rows r0, r0+8; swizzled group
    const int strow = lane >> 3;                     // 0..7
    const int sgrp  = (lane & 7) ^ strow;            // group ^ (row&7)
    const int r0    = wave * 16 + strow;
    const int dstoff = wave * 1024 + lane * 8;       // ushort elems; +512 for i=1

    // prologue: stage tile 0 into buf 0
    gload_lds16(Kw + base + (size_t)r0 * HDIM + sgrp * 8,        &Kbuf[0][dstoff]);
    gload_lds16(Kw + base + (size_t)(r0 + 8) * HDIM + sgrp * 8,  &Kbuf[0][dstoff + 512]);
    gload_lds16(Vw + base + (size_t)r0 * S_LEN + sgrp * 8,       &Vbuf[0][dstoff]);
    gload_lds16(Vw + base + (size_t)(r0 + 8) * S_LEN + sgrp * 8, &Vbuf[0][dstoff + 512]);
    __syncthreads();

    int cur = 0;
    for (int t = 0; t < NT; ++t) {
        // stage next tile into buf[cur^1] (in-flight across this tile's compute)
        if (t + 1 < NT) {
            const int sn = (t + 1) * 64;
            gload_lds16(Kw + base + (size_t)(sn + r0) * HDIM + sgrp * 8,       &Kbuf[cur ^ 1][dstoff]);
            gload_lds16(Kw + base + (size_t)(sn + r0 + 8) * HDIM + sgrp * 8,   &Kbuf[cur ^ 1][dstoff + 512]);
            gload_lds16(Vw + base + (size_t)r0 * S_LEN + sn + sgrp * 8,        &Vbuf[cur ^ 1][dstoff]);
            gload_lds16(Vw + base + (size_t)(r0 + 8) * S_LEN + sn + sgrp * 8,  &Vbuf[cur ^ 1][dstoff + 512]);
        }

        const unsigned short* Klds = Kbuf[cur];
        const unsigned short* Vlds = Vbuf[cur];

        // S^T = K . Q^T (two 32-key tiles); A and B share the slot->k map.
        f32x16 S0, S1;
#pragma unroll
        for (int i = 0; i < 16; ++i) { S0[i] = 0.f; S1[i] = 0.f; }
        __builtin_amdgcn_s_setprio(1);
#pragma unroll
        for (int c = 0; c < 4; ++c) {
            const int g = ((c * 2 + half) ^ (l31 & 7)) * 8;
            const bf16x8 ka0 = *(const bf16x8*)&Klds[l31 * 64 + g];
            const bf16x8 ka1 = *(const bf16x8*)&Klds[(32 + l31) * 64 + g];
            S0 = __builtin_amdgcn_mfma_f32_32x32x16_bf16(ka0, qf[c], S0, 0, 0, 0);
            S1 = __builtin_amdgcn_mfma_f32_32x32x16_bf16(ka1, qf[c], S1, 0, 0, 0);
        }
        __builtin_amdgcn_s_setprio(0);

        // ---- in-register online softmax (base 2), defer-max THR=8 ----
        f32x16 mx16;
#pragma unroll
        for (int i = 0; i < 16; ++i) mx16[i] = fmaxf(S0[i], S1[i]);
        float m8[8], m4[4], m2[2];
#pragma unroll
        for (int i = 0; i < 8; ++i) m8[i] = fmaxf(mx16[i], mx16[i + 8]);
#pragma unroll
        for (int i = 0; i < 4; ++i) m4[i] = fmaxf(m8[i], m8[i + 4]);
        m2[0] = fmaxf(m4[0], m4[2]); m2[1] = fmaxf(m4[1], m4[3]);
        float mx = fmaxf(m2[0], m2[1]);
        mx = fmaxf(mx, __shfl_xor(mx, 32, 64));      // combine lane halves

        if (!__all(mx - mrun <= 8.0f)) {             // wave-uniform rescale
            const float mnew = fmaxf(mrun, mx);
            const float ex   = exp2f(mrun - mnew);
            mrun = mnew;
            lrun *= ex;
            Od0 *= ex;
            Od1 *= ex;
        }

#pragma unroll
        for (int i = 0; i < 16; ++i) S0[i] = exp2f(S0[i] - mrun);
#pragma unroll
        for (int i = 0; i < 16; ++i) S1[i] = exp2f(S1[i] - mrun);
        f32x16 sv = S0 + S1;
        float s8[8], s4[4];
#pragma unroll
        for (int i = 0; i < 8; ++i) s8[i] = sv[i] + sv[i + 8];
#pragma unroll
        for (int i = 0; i < 4; ++i) s4[i] = s8[i] + s8[i + 4];
        float psum = (s4[0] + s4[2]) + (s4[1] + s4[3]);
        psum += __shfl_xor(psum, 32, 64);
        lrun += psum;

        // ---- P^T -> per-wave LDS as packed key-pairs (C/D layout, m74/m101) ----
#pragma unroll
        for (int w = 0; w < 8; ++w) {
            const unsigned int pk0 = (unsigned int)f2bf(S0[2 * w])
                                   | ((unsigned int)f2bf(S0[2 * w + 1]) << 16);
            const unsigned int pk1 = (unsigned int)f2bf(S1[2 * w])
                                   | ((unsigned int)f2bf(S1[2 * w + 1]) << 16);
            const int kp = (w & 1) + 4 * (w >> 1) + 2 * half;
            Pu[wave][kp * 32 + l31]        = pk0;
            Pu[wave][(16 + kp) * 32 + l31] = pk1;
        }
        __asm__ volatile("" ::: "memory");

        // ---- PV: O^T[d][q] += V^T . P^T (same slot->key map as V frags) ----
        __builtin_amdgcn_s_setprio(1);
#pragma unroll
        for (int c = 0; c < 4; ++c) {
            const int g = ((c * 2 + half) ^ (l31 & 7)) * 8;
            const bf16x8 va0 = *(const bf16x8*)&Vlds[l31 * 64 + g];
            const bf16x8 va1 = *(const bf16x8*)&Vlds[(32 + l31) * 64 + g];
            u32x4 pu;
#pragma unroll
            for (int e = 0; e < 4; ++e)
                pu[e] = Pu[wave][(c * 8 + half * 4 + e) * 32 + l31];
            const bf16x8 pb = __builtin_bit_cast(bf16x8, pu);
            Od0 = __builtin_amdgcn_mfma_f32_32x32x16_bf16(va0, pb, Od0, 0, 0, 0);
            Od1 = __builtin_amdgcn_mfma_f32_32x32x16_bf16(va1, pb, Od1, 0, 0, 0);
        }
        __builtin_amdgcn_s_setprio(0);

        __syncthreads();   // drains stage loads (vmcnt0) + orders buffers
        cur ^= 1;
    }

    // epilogue: normalize, write fp32 out[s][b][h*64+d]
    const int bb = bh >> 4;
    const int hh = bh & 15;
    const float inv = 1.0f / lrun;
    float* op = out + (size_t)qrow * (BATCH * DMODEL) + bb * DMODEL + hh * HDIM;
#pragma unroll
    for (int gg = 0; gg < 4; ++gg) {
        const int d0 = gg * 8 + half * 4;
        float4 v0, v1;
        v0.x = Od0[gg * 4 + 0] * inv; v0.y = Od0[gg * 4 + 1] * inv;
        v0.z = Od0[gg * 4 + 2] * inv; v0.w = Od0[gg * 4 + 3] * inv;
        v1.x = Od1[gg * 4 + 0] * inv; v1.y = Od1[gg * 4 + 1] * inv;
        v1.z = Od1[gg * 4 + 2] * inv; v1.w = Od1[gg * 4 + 3] * inv;
        *(float4*)(op + d0)      = v0;
        *(float4*)(op + 32 + d0) = v1;
    }
}

extern "C" void kernel_launch(void* const* d_in, const int* in_sizes, int n_in,
                              void* d_out, int out_size, void* d_ws, size_t ws_size,
                              hipStream_t stream) {
    const float* q  = (const float*)d_in[0];
    const float* k  = (const float*)d_in[1];
    const float* v  = (const float*)d_in[2];
    const float* Wq = (const float*)d_in[3];
    const float* bq = (const float*)d_in[4];
    const float* Wk = (const float*)d_in[5];
    const float* bk = (const float*)d_in[6];
    const float* Wv = (const float*)d_in[7];
    const float* bv = (const float*)d_in[8];
    unsigned short* ws = (unsigned short*)d_ws;
    float* out = (float*)d_out;

    dim3 pgrid(DMODEL / PBN, MTOT / PBM, 3);
    proj_kernel<<<pgrid, dim3(256), 0, stream>>>(q, k, v, Wq, Wk, Wv, bq, bk, bv, ws);

    attn_kernel<<<dim3(512), dim3(256), 0, stream>>>(ws, out);
}